// Round 5
// baseline (1032.905 us; speedup 1.0000x reference)
//
#include <hip/hip_runtime.h>

#define DF   512
#define HID2 512
#define NHID 256
#define NCLS 50
#define NB   512
#define TAIL_BLOCKS 704u

typedef __attribute__((ext_vector_type(8))) short short8;
typedef __attribute__((ext_vector_type(4))) float float4v;

__device__ __forceinline__ float b2f(unsigned short u) {
    union { unsigned int i; float f; } v; v.i = ((unsigned int)u) << 16; return v.f;
}
__device__ __forceinline__ unsigned short f2b(float f) {
    union { float f; unsigned int u; } v; v.f = f;
    unsigned int r = v.u + 0x7FFFu + ((v.u >> 16) & 1u);
    return (unsigned short)(r >> 16);
}
__device__ __forceinline__ float blo(unsigned int u) {
    union { unsigned int i; float f; } v; v.i = u << 16; return v.f;
}
__device__ __forceinline__ float bhi(unsigned int u) {
    union { unsigned int i; float f; } v; v.i = u & 0xFFFF0000u; return v.f;
}
__device__ __forceinline__ unsigned int pk2(float a, float b) {
    return (unsigned int)f2b(a) | ((unsigned int)f2b(b) << 16);
}

// device-scope software grid barrier (single-use counter; all blocks co-resident
// by construction: __launch_bounds__(256,3) -> >=3 blocks/CU -> 768 >= 704).
__device__ __forceinline__ void gbar(unsigned int* ctr, unsigned int target) {
    __syncthreads();
    __threadfence();
    if (threadIdx.x == 0) {
        __hip_atomic_fetch_add(ctr, 1u, __ATOMIC_RELEASE, __HIP_MEMORY_SCOPE_AGENT);
        while (__hip_atomic_load(ctr, __ATOMIC_ACQUIRE, __HIP_MEMORY_SCOPE_AGENT) < target) {
            __builtin_amdgcn_s_sleep(8);
        }
    }
    __syncthreads();
    __threadfence();
}

// ---- preprocess mega-kernel: all independent prep work in ONE dispatch -----
// HEAVY-FIRST block roles (256 threads each):
//   [0,2560)      : h2mean = mean25(feat[s2]) (5120 groups, 2/block)  [heavy]
//   [2560,2816)   : h1mean = mean10(feat[s1]) (512 groups, 2/block)   [medium]
//   [2816,2944)   : weight transpose fp32->bf16 (4 weights, 8x4 tiles)
//   [2944,3200)   : gather h0 rows (512 rows, 2/block)
//   [3200,5760)   : gather h1 rows (5120 rows, 2/block)
// Also zeroes the tail kernel's grid-barrier counters (stream-ordered).
__global__ __launch_bounds__(256) void preprocess(
        const float* __restrict__ feat,
        const float* __restrict__ W0, const float* __restrict__ W1,
        const float* __restrict__ W2, const float* __restrict__ W3,
        unsigned short* __restrict__ Wt,
        const int* __restrict__ s0, const int* __restrict__ s1,
        const int* __restrict__ s2,
        unsigned short* __restrict__ h0bf, unsigned short* __restrict__ h1bf,
        unsigned short* __restrict__ h1mean, unsigned short* __restrict__ h2mean,
        unsigned int* __restrict__ bars) {
    __shared__ unsigned short T[64][66];
    const int b = blockIdx.x;
    const int t = threadIdx.x;

    if (b == 0 && t == 0) { bars[0] = 0u; bars[1] = 0u; }

    if (b >= 2816 && b < 2944) {
        // weight transpose: W [512 k][256 n] fp32 -> Wt [256 n][512 k] bf16
        const int w = b - 2816;
        const int x = w & 7, y = (w >> 3) & 3, z = w >> 5;
        const float* W = (z == 0) ? W0 : (z == 1) ? W1 : (z == 2) ? W2 : W3;
        unsigned short* Out = Wt + (size_t)z * NHID * DF;
        const int k0 = x * 64, n0 = y * 64;
#pragma unroll
        for (int p = 0; p < 4; ++p) {
            const int k = p * 16 + (t >> 4);
            const int n = (t & 15) * 4;
            const float4 v = *(const float4*)(W + (size_t)(k0 + k) * NHID + n0 + n);
            T[n + 0][k] = f2b(v.x);
            T[n + 1][k] = f2b(v.y);
            T[n + 2][k] = f2b(v.z);
            T[n + 3][k] = f2b(v.w);
        }
        __syncthreads();
#pragma unroll
        for (int p = 0; p < 4; ++p) {
            const int n = p * 16 + (t >> 4);
            const int k = (t & 15) * 4;
            ushort4 o;
            o.x = T[n][k]; o.y = T[n][k + 1]; o.z = T[n][k + 2]; o.w = T[n][k + 3];
            *(ushort4*)(Out + (size_t)(n0 + n) * DF + k0 + k) = o;
        }
        return;
    }

    const int sub = t >> 7;          // 0/1: which row/group of this block
    const int col = (t & 127) * 4;   // float column offset (128 lanes x float4 = 2KB row)

    if (b < 2560) {                  // h2mean (mean of 25 feature rows) — heavy first
        const int g = b * 2 + sub;
        float ax = 0.f, ay = 0.f, az = 0.f, aw = 0.f;
#pragma unroll
        for (int j = 0; j < 25; ++j) {
            const float4 v = *(const float4*)(feat + (size_t)s2[g * 25 + j] * DF + col);
            ax += v.x; ay += v.y; az += v.z; aw += v.w;
        }
        const float inv = 1.f / 25.f;
        ushort4 o;
        o.x = f2b(ax * inv); o.y = f2b(ay * inv);
        o.z = f2b(az * inv); o.w = f2b(aw * inv);
        *(ushort4*)(h2mean + (size_t)g * DF + col) = o;
        return;
    }
    if (b < 2816) {                  // h1mean (fp32-accurate mean of 10 feature rows)
        const int g = (b - 2560) * 2 + sub;
        float ax = 0.f, ay = 0.f, az = 0.f, aw = 0.f;
#pragma unroll
        for (int j = 0; j < 10; ++j) {
            const float4 v = *(const float4*)(feat + (size_t)s1[g * 10 + j] * DF + col);
            ax += v.x; ay += v.y; az += v.z; aw += v.w;
        }
        ushort4 o;
        o.x = f2b(ax * 0.1f); o.y = f2b(ay * 0.1f);
        o.z = f2b(az * 0.1f); o.w = f2b(aw * 0.1f);
        *(ushort4*)(h1mean + (size_t)g * DF + col) = o;
        return;
    }
    if (b < 3200) {                  // gather h0 (b in [2944,3200))
        const int r = (b - 2944) * 2 + sub;
        const float4 v = *(const float4*)(feat + (size_t)s0[r] * DF + col);
        ushort4 o; o.x = f2b(v.x); o.y = f2b(v.y); o.z = f2b(v.z); o.w = f2b(v.w);
        *(ushort4*)(h0bf + (size_t)r * DF + col) = o;
        return;
    }
    {                                // gather h1 (b in [3200,5760))
        const int r = (b - 3200) * 2 + sub;
        const float4 v = *(const float4*)(feat + (size_t)s1[r] * DF + col);
        ushort4 o; o.x = f2b(v.x); o.y = f2b(v.y); o.z = f2b(v.z); o.w = f2b(v.w);
        *(ushort4*)(h1bf + (size_t)r * DF + col) = o;
    }
}

// ---- fused tail: GEMM1 (704 blocks) -> gbar -> GEMM2 (64) -> gbar ->
//      normalize+pred (512). One dispatch, two device grid barriers.
// Phase arithmetic is byte-identical to the previously-passing split kernels.
__global__ __launch_bounds__(256, 3) void fused_tail(
        const unsigned short* __restrict__ h1bf, const unsigned short* __restrict__ h2mean,
        const unsigned short* __restrict__ h0bf, const unsigned short* __restrict__ h1mean,
        const unsigned short* __restrict__ Wt_s0, const unsigned short* __restrict__ Wt_n0,
        const unsigned short* __restrict__ Wt_s1, const unsigned short* __restrict__ Wt_n1,
        unsigned short* __restrict__ n1, unsigned short* __restrict__ n0rows,
        float* __restrict__ outb,
        const float* __restrict__ Wp, const float* __restrict__ bp,
        float* __restrict__ logits,
        unsigned int* __restrict__ bars) {
    __shared__ union {
        struct { unsigned short As[64][72]; unsigned short Bs[64][72]; } g;
        struct { float row[HID2]; float red[256]; float part[4][64]; } nz;
    } sm;

    const int bid = blockIdx.x;
    const int tid = threadIdx.x;
    const int wave = tid >> 6;
    const int lane = tid & 63;
    const int sr = tid >> 3;          // 0..31 staging row
    const int sk = (tid & 7) * 8;     // staging k offset (8 bf16 = 16B)
    const int am = wave * 16 + (lane & 15);
    const int kq = (lane >> 4) * 8;

    // ---------------- Phase A: layer-0 GEMMs (all 704 blocks) ---------------
    {
        const int xb = bid & 7;             // n-tile 0..7
        const int yb = bid >> 3;            // 0..87
        const bool second = (yb >= 80);
        const int m0 = (second ? (yb - 80) : yb) * 64;
        const int nb = xb * 64;
        const unsigned short* A1 = second ? h0bf : h1bf;
        const unsigned short* A2 = second ? h1mean : h2mean;
        unsigned short* C = second ? n0rows : n1;
        const unsigned short* A  = (nb < 256) ? A1 : A2;
        const unsigned short* Wt = (nb < 256) ? Wt_s0 : Wt_n0;
        const int n0 = nb & 255;

        float4v acc[4];
#pragma unroll
        for (int i = 0; i < 4; ++i) acc[i] = (float4v)(0.f);

        for (int k0 = 0; k0 < DF; k0 += 64) {
            *(uint4*)&sm.g.As[sr][sk]      = *(const uint4*)(A  + (size_t)(m0 + sr) * DF + k0 + sk);
            *(uint4*)&sm.g.As[sr + 32][sk] = *(const uint4*)(A  + (size_t)(m0 + sr + 32) * DF + k0 + sk);
            *(uint4*)&sm.g.Bs[sr][sk]      = *(const uint4*)(Wt + (size_t)(n0 + sr) * DF + k0 + sk);
            *(uint4*)&sm.g.Bs[sr + 32][sk] = *(const uint4*)(Wt + (size_t)(n0 + sr + 32) * DF + k0 + sk);
            __syncthreads();
#pragma unroll
            for (int ks = 0; ks < 64; ks += 32) {
                const short8 af = *(const short8*)&sm.g.As[am][ks + kq];
#pragma unroll
                for (int nt = 0; nt < 4; ++nt) {
                    const short8 bf = *(const short8*)&sm.g.Bs[nt * 16 + (lane & 15)][ks + kq];
                    acc[nt] = __builtin_amdgcn_mfma_f32_16x16x32_bf16(af, bf, acc[nt], 0, 0, 0);
                }
            }
            __syncthreads();
        }

#pragma unroll
        for (int nt = 0; nt < 4; ++nt) {
            const int gcol = nb + nt * 16 + (lane & 15);
#pragma unroll
            for (int r = 0; r < 4; ++r) {
                const int grow = m0 + wave * 16 + (lane >> 4) * 4 + r;
                const float v = fmaxf(acc[nt][r], 0.f);
                C[(size_t)grow * HID2 + gcol] = f2b(v);
            }
        }
    }

    gbar(&bars[0], TAIL_BLOCKS);

    // ---------------- Phase B: final GEMM with inline n1mean (64 blocks) ----
    if (bid < 64) {
        const int xb = bid & 7;
        const int m0 = (bid >> 3) * 64;
        const int nb = xb * 64;
        const bool meanpath = (nb >= 256);
        const unsigned short* Wt = meanpath ? Wt_n1 : Wt_s1;
        const int n0 = nb & 255;

        float4v acc[4];
#pragma unroll
        for (int i = 0; i < 4; ++i) acc[i] = (float4v)(0.f);

        for (int k0 = 0; k0 < DF; k0 += 64) {
            if (!meanpath) {
                *(uint4*)&sm.g.As[sr][sk]      = *(const uint4*)(n0rows + (size_t)(m0 + sr) * DF + k0 + sk);
                *(uint4*)&sm.g.As[sr + 32][sk] = *(const uint4*)(n0rows + (size_t)(m0 + sr + 32) * DF + k0 + sk);
            } else {
                // inline mean10 of n1 rows (identical to old mean_bf16 numerics)
#pragma unroll
                for (int h = 0; h < 2; ++h) {
                    const int r = sr + h * 32;
                    const size_t gbase = (size_t)(m0 + r) * 10;
                    float a0 = 0.f, a1 = 0.f, a2 = 0.f, a3 = 0.f;
                    float a4 = 0.f, a5 = 0.f, a6 = 0.f, a7 = 0.f;
#pragma unroll
                    for (int j = 0; j < 10; ++j) {
                        const uint4 v = *(const uint4*)(n1 + (gbase + j) * DF + k0 + sk);
                        a0 += blo(v.x); a1 += bhi(v.x);
                        a2 += blo(v.y); a3 += bhi(v.y);
                        a4 += blo(v.z); a5 += bhi(v.z);
                        a6 += blo(v.w); a7 += bhi(v.w);
                    }
                    uint4 o;
                    o.x = pk2(a0 * 0.1f, a1 * 0.1f);
                    o.y = pk2(a2 * 0.1f, a3 * 0.1f);
                    o.z = pk2(a4 * 0.1f, a5 * 0.1f);
                    o.w = pk2(a6 * 0.1f, a7 * 0.1f);
                    *(uint4*)&sm.g.As[r][sk] = o;
                }
            }
            *(uint4*)&sm.g.Bs[sr][sk]      = *(const uint4*)(Wt + (size_t)(n0 + sr) * DF + k0 + sk);
            *(uint4*)&sm.g.Bs[sr + 32][sk] = *(const uint4*)(Wt + (size_t)(n0 + sr + 32) * DF + k0 + sk);
            __syncthreads();
#pragma unroll
            for (int ks = 0; ks < 64; ks += 32) {
                const short8 af = *(const short8*)&sm.g.As[am][ks + kq];
#pragma unroll
                for (int nt = 0; nt < 4; ++nt) {
                    const short8 bf = *(const short8*)&sm.g.Bs[nt * 16 + (lane & 15)][ks + kq];
                    acc[nt] = __builtin_amdgcn_mfma_f32_16x16x32_bf16(af, bf, acc[nt], 0, 0, 0);
                }
            }
            __syncthreads();
        }

#pragma unroll
        for (int nt = 0; nt < 4; ++nt) {
            const int gcol = nb + nt * 16 + (lane & 15);
#pragma unroll
            for (int r = 0; r < 4; ++r) {
                const int grow = m0 + wave * 16 + (lane >> 4) * 4 + r;
                outb[(size_t)grow * HID2 + gcol] = acc[nt][r];
            }
        }
    }

    gbar(&bars[1], TAIL_BLOCKS);

    // ---------------- Phase C: normalize + prediction head (512 blocks) -----
    if (bid < NB) {
        const int r = bid;
        const int t = tid;
        const float2 v = *(const float2*)(outb + (size_t)r * HID2 + t * 2);
        sm.nz.row[t * 2] = v.x;
        sm.nz.row[t * 2 + 1] = v.y;
        sm.nz.red[t] = v.x * v.x + v.y * v.y;
        __syncthreads();
        for (int s = 128; s > 0; s >>= 1) {
            if (t < s) sm.nz.red[t] += sm.nz.red[t + s];
            __syncthreads();
        }
        const float scale = 1.0f / fmaxf(sqrtf(sm.nz.red[0]), 1e-12f);
        const int c = t & 63;        // output class (valid < 50)
        const int q = t >> 6;        // K-chunk (wave index)
        float acc = 0.f;
        if (c < NCLS) {
#pragma unroll 4
            for (int k = q * 128; k < q * 128 + 128; ++k) acc += sm.nz.row[k] * Wp[k * NCLS + c];
        }
        sm.nz.part[q][c] = acc;
        __syncthreads();
        if (t < NCLS) {
            logits[r * NCLS + t] =
                (sm.nz.part[0][t] + sm.nz.part[1][t] + sm.nz.part[2][t] + sm.nz.part[3][t]) * scale + bp[t];
        }
    }
}

extern "C" void kernel_launch(void* const* d_in, const int* in_sizes, int n_in,
                              void* d_out, int out_size, void* d_ws, size_t ws_size,
                              hipStream_t stream) {
    const float* feat    = (const float*)d_in[0];
    const float* Wself0  = (const float*)d_in[1];
    const float* Wneigh0 = (const float*)d_in[2];
    const float* Wself1  = (const float*)d_in[3];
    const float* Wneigh1 = (const float*)d_in[4];
    const float* Wpred   = (const float*)d_in[5];
    const float* bpred   = (const float*)d_in[6];
    const int* s0 = (const int*)d_in[7];
    const int* s1 = (const int*)d_in[8];
    const int* s2 = (const int*)d_in[9];

    unsigned short* u = (unsigned short*)d_ws;
    unsigned short* h2mean = u;                         // 5120*512
    unsigned short* h1bf   = h2mean + 5120 * 512;       // 5120*512
    unsigned short* n1     = h1bf   + 5120 * 512;       // 5120*512
    unsigned short* h1mean = n1     + 5120 * 512;       // 512*512
    unsigned short* h0bf   = h1mean + 512 * 512;        // 512*512
    unsigned short* n1mean = h0bf   + 512 * 512;        // 512*512 (unused)
    unsigned short* n0     = n1mean + 512 * 512;        // 512*512
    unsigned short* Wt     = n0     + 512 * 512;        // 4 * 256*512
    float* outb = (float*)(Wt + 4 * NHID * DF);         // 512*512 fp32
    unsigned int* bars = (unsigned int*)(outb + 512 * 512);  // 2 barrier counters
    unsigned short* Wt_s0 = Wt;
    unsigned short* Wt_n0 = Wt + 1 * NHID * DF;
    unsigned short* Wt_s1 = Wt + 2 * NHID * DF;
    unsigned short* Wt_n1 = Wt + 3 * NHID * DF;

    // L1: all independent preprocessing (heavy blocks first) + barrier init
    preprocess<<<5760, 256, 0, stream>>>(feat, Wself0, Wneigh0, Wself1, Wneigh1, Wt,
                                         s0, s1, s2, h0bf, h1bf, h1mean, h2mean, bars);
    // L2: GEMM1 + GEMM2(inline n1mean) + normalize/pred, one dispatch
    fused_tail<<<TAIL_BLOCKS, 256, 0, stream>>>(h1bf, h2mean, h0bf, h1mean,
                                                Wt_s0, Wt_n0, Wt_s1, Wt_n1,
                                                n1, n0, outb, Wpred, bpred,
                                                (float*)d_out, bars);
}

// Round 6
// 545.658 us; speedup vs baseline: 1.8930x; 1.8930x over previous
//
#include <hip/hip_runtime.h>

#define DF   512
#define HID2 512
#define NHID 256
#define NCLS 50
#define NB   512

typedef __attribute__((ext_vector_type(8))) short short8;
typedef __attribute__((ext_vector_type(4))) float float4v;

typedef __attribute__((address_space(1))) unsigned int gas_u32;
typedef __attribute__((address_space(3))) unsigned int las_u32;

__device__ __forceinline__ float b2f(unsigned short u) {
    union { unsigned int i; float f; } v; v.i = ((unsigned int)u) << 16; return v.f;
}
__device__ __forceinline__ unsigned short f2b(float f) {
    union { float f; unsigned int u; } v; v.f = f;
    unsigned int r = v.u + 0x7FFFu + ((v.u >> 16) & 1u);
    return (unsigned short)(r >> 16);
}
__device__ __forceinline__ float blo(unsigned int u) {
    union { unsigned int i; float f; } v; v.i = u << 16; return v.f;
}
__device__ __forceinline__ float bhi(unsigned int u) {
    union { unsigned int i; float f; } v; v.i = u & 0xFFFF0000u; return v.f;
}
__device__ __forceinline__ unsigned int pk2(float a, float b) {
    return (unsigned int)f2b(a) | ((unsigned int)f2b(b) << 16);
}

// async 16B global->LDS (lane l of the wave lands at ldsbase + l*16).
// AS casts via integer (replicates LLVM's own addrspacecast lowering:
// flat->AS(3) is trunc-to-32, flat->AS(1) is a no-op).
__device__ __forceinline__ void g2lds16(const unsigned short* g, const unsigned short* ldsbase) {
    __builtin_amdgcn_global_load_lds(
        (gas_u32*)(unsigned long long)g,
        (las_u32*)(unsigned int)(unsigned long long)ldsbase,
        16, 0, 0);
}

// ---- preprocess mega-kernel: all independent prep work in ONE dispatch -----
// HEAVY-FIRST block roles (256 threads each):
//   [0,2560)      : h2mean = mean25(feat[s2]) (5120 groups, 2/block)  [heavy]
//   [2560,2816)   : h1mean = mean10(feat[s1]) (512 groups, 2/block)   [medium]
//   [2816,2944)   : weight transpose fp32->bf16 (4 weights, 8x4 tiles)
//   [2944,3200)   : gather h0 rows (512 rows, 2/block)
//   [3200,5760)   : gather h1 rows (5120 rows, 2/block)
__global__ __launch_bounds__(256) void preprocess(
        const float* __restrict__ feat,
        const float* __restrict__ W0, const float* __restrict__ W1,
        const float* __restrict__ W2, const float* __restrict__ W3,
        unsigned short* __restrict__ Wt,
        const int* __restrict__ s0, const int* __restrict__ s1,
        const int* __restrict__ s2,
        unsigned short* __restrict__ h0bf, unsigned short* __restrict__ h1bf,
        unsigned short* __restrict__ h1mean, unsigned short* __restrict__ h2mean) {
    __shared__ unsigned short T[64][66];
    const int b = blockIdx.x;
    const int t = threadIdx.x;

    if (b >= 2816 && b < 2944) {
        // weight transpose: W [512 k][256 n] fp32 -> Wt [256 n][512 k] bf16
        const int w = b - 2816;
        const int x = w & 7, y = (w >> 3) & 3, z = w >> 5;
        const float* W = (z == 0) ? W0 : (z == 1) ? W1 : (z == 2) ? W2 : W3;
        unsigned short* Out = Wt + (size_t)z * NHID * DF;
        const int k0 = x * 64, n0 = y * 64;
#pragma unroll
        for (int p = 0; p < 4; ++p) {
            const int k = p * 16 + (t >> 4);
            const int n = (t & 15) * 4;
            const float4 v = *(const float4*)(W + (size_t)(k0 + k) * NHID + n0 + n);
            T[n + 0][k] = f2b(v.x);
            T[n + 1][k] = f2b(v.y);
            T[n + 2][k] = f2b(v.z);
            T[n + 3][k] = f2b(v.w);
        }
        __syncthreads();
#pragma unroll
        for (int p = 0; p < 4; ++p) {
            const int n = p * 16 + (t >> 4);
            const int k = (t & 15) * 4;
            ushort4 o;
            o.x = T[n][k]; o.y = T[n][k + 1]; o.z = T[n][k + 2]; o.w = T[n][k + 3];
            *(ushort4*)(Out + (size_t)(n0 + n) * DF + k0 + k) = o;
        }
        return;
    }

    const int sub = t >> 7;          // 0/1: which row/group of this block
    const int col = (t & 127) * 4;   // float column offset (128 lanes x float4 = 2KB row)

    if (b < 2560) {                  // h2mean (mean of 25 feature rows) — heavy first
        const int g = b * 2 + sub;
        float ax = 0.f, ay = 0.f, az = 0.f, aw = 0.f;
#pragma unroll
        for (int j = 0; j < 25; ++j) {
            const float4 v = *(const float4*)(feat + (size_t)s2[g * 25 + j] * DF + col);
            ax += v.x; ay += v.y; az += v.z; aw += v.w;
        }
        const float inv = 1.f / 25.f;
        ushort4 o;
        o.x = f2b(ax * inv); o.y = f2b(ay * inv);
        o.z = f2b(az * inv); o.w = f2b(aw * inv);
        *(ushort4*)(h2mean + (size_t)g * DF + col) = o;
        return;
    }
    if (b < 2816) {                  // h1mean (fp32-accurate mean of 10 feature rows)
        const int g = (b - 2560) * 2 + sub;
        float ax = 0.f, ay = 0.f, az = 0.f, aw = 0.f;
#pragma unroll
        for (int j = 0; j < 10; ++j) {
            const float4 v = *(const float4*)(feat + (size_t)s1[g * 10 + j] * DF + col);
            ax += v.x; ay += v.y; az += v.z; aw += v.w;
        }
        ushort4 o;
        o.x = f2b(ax * 0.1f); o.y = f2b(ay * 0.1f);
        o.z = f2b(az * 0.1f); o.w = f2b(aw * 0.1f);
        *(ushort4*)(h1mean + (size_t)g * DF + col) = o;
        return;
    }
    if (b < 3200) {                  // gather h0 (b in [2944,3200))
        const int r = (b - 2944) * 2 + sub;
        const float4 v = *(const float4*)(feat + (size_t)s0[r] * DF + col);
        ushort4 o; o.x = f2b(v.x); o.y = f2b(v.y); o.z = f2b(v.z); o.w = f2b(v.w);
        *(ushort4*)(h0bf + (size_t)r * DF + col) = o;
        return;
    }
    {                                // gather h1 (b in [3200,5760))
        const int r = (b - 3200) * 2 + sub;
        const float4 v = *(const float4*)(feat + (size_t)s1[r] * DF + col);
        ushort4 o; o.x = f2b(v.x); o.y = f2b(v.y); o.z = f2b(v.z); o.w = f2b(v.w);
        *(ushort4*)(h1bf + (size_t)r * DF + col) = o;
    }
}

// ---- fused layer-0 GEMMs: n1 (M=5120, y<80) and n0 (M=512, y>=80) ----------
// C[M,512] = relu([A1@W1, A2@W2]); bf16 out. Tile 64m x 64n, BK=64, 4 waves.
// Staging via global_load_lds (16B/lane) into LINEAR [64][64] LDS with
// both-sides XOR swizzle (G21): source col16' = (l&7)^(l>>3); read slot
// k16 ^ (row&7). Writes conflict-free by construction; reads 2-way (free).
__global__ __launch_bounds__(256) void gemm_fused01(
        const unsigned short* __restrict__ A1a, const unsigned short* __restrict__ A2a,
        const unsigned short* __restrict__ A1b, const unsigned short* __restrict__ A2b,
        const unsigned short* __restrict__ W1t, const unsigned short* __restrict__ W2t,
        unsigned short* __restrict__ C1, unsigned short* __restrict__ C2) {
    __shared__ __attribute__((aligned(16))) unsigned short As[64 * 64];
    __shared__ __attribute__((aligned(16))) unsigned short Bs[64 * 64];
    const int tid = threadIdx.x;
    const int wave = tid >> 6;
    const int lane = tid & 63;
    const bool second = (blockIdx.y >= 80);
    const int m0 = (second ? (blockIdx.y - 80) : blockIdx.y) * 64;
    const int nb = blockIdx.x * 64;
    const unsigned short* A1 = second ? A1b : A1a;
    const unsigned short* A2 = second ? A2b : A2a;
    unsigned short* C = second ? C2 : C1;
    const unsigned short* A  = (nb < 256) ? A1 : A2;
    const unsigned short* Wt = (nb < 256) ? W1t : W2t;
    const int n0 = nb & 255;

    // staging geometry: wave w stages rows w*16..w*16+15 (2 calls x 8 rows)
    const int lrow = lane >> 3;                 // 0..7 row within the 8-row call
    const int scol = ((lane & 7) ^ lrow) * 8;   // pre-swizzled source col (ushorts)
    const int wrow = wave * 16;

    float4v acc[4];
#pragma unroll
    for (int i = 0; i < 4; ++i) acc[i] = (float4v)(0.f);

    const int am  = wave * 16 + (lane & 15);    // A row this lane consumes
    const int sw  = lane & 7;                   // row&7 for both am and br
    const int kqw = lane >> 4;                  // k16 quarter offset 0..3

    for (int k0 = 0; k0 < DF; k0 += 64) {
#pragma unroll
        for (int q = 0; q < 2; ++q) {
            const int r = wrow + q * 8;
            g2lds16(A  + (size_t)(m0 + r + lrow) * DF + k0 + scol, &As[r * 64]);
            g2lds16(Wt + (size_t)(n0 + r + lrow) * DF + k0 + scol, &Bs[r * 64]);
        }
        __syncthreads();
#pragma unroll
        for (int ks16 = 0; ks16 < 8; ks16 += 4) {
            const int k16 = ks16 + kqw;
            const short8 af = *(const short8*)&As[am * 64 + ((k16 ^ sw) << 3)];
#pragma unroll
            for (int nt = 0; nt < 4; ++nt) {
                const int br = nt * 16 + (lane & 15);
                const short8 bf = *(const short8*)&Bs[br * 64 + ((k16 ^ sw) << 3)];
                acc[nt] = __builtin_amdgcn_mfma_f32_16x16x32_bf16(af, bf, acc[nt], 0, 0, 0);
            }
        }
        __syncthreads();
    }

#pragma unroll
    for (int nt = 0; nt < 4; ++nt) {
        const int gcol = nb + nt * 16 + (lane & 15);
#pragma unroll
        for (int r = 0; r < 4; ++r) {
            const int grow = m0 + wave * 16 + (lane >> 4) * 4 + r;
            const float v = fmaxf(acc[nt][r], 0.f);
            C[(size_t)grow * HID2 + gcol] = f2b(v);
        }
    }
}

// ---- final layer-1 GEMM with INLINE n1mean (round-4 verified, unchanged) ---
__global__ __launch_bounds__(256) void gemm_final(
        const unsigned short* __restrict__ n0rows,
        const unsigned short* __restrict__ n1rows,
        const unsigned short* __restrict__ W1t, const unsigned short* __restrict__ W2t,
        float* __restrict__ Cout) {
    __shared__ unsigned short As[64][72];
    __shared__ unsigned short Bs[64][72];
    const int tid = threadIdx.x;
    const int wave = tid >> 6;
    const int lane = tid & 63;
    const int m0 = blockIdx.y * 64;
    const int nb = blockIdx.x * 64;
    const bool meanpath = (nb >= 256);
    const unsigned short* Wt = meanpath ? W2t : W1t;
    const int n0 = nb & 255;

    const int sr = tid >> 3;
    const int sk = (tid & 7) * 8;

    float4v acc[4];
#pragma unroll
    for (int i = 0; i < 4; ++i) acc[i] = (float4v)(0.f);

    const int am = wave * 16 + (lane & 15);
    const int kq = (lane >> 4) * 8;

    for (int k0 = 0; k0 < DF; k0 += 64) {
        if (!meanpath) {
            *(uint4*)&As[sr][sk]      = *(const uint4*)(n0rows + (size_t)(m0 + sr) * DF + k0 + sk);
            *(uint4*)&As[sr + 32][sk] = *(const uint4*)(n0rows + (size_t)(m0 + sr + 32) * DF + k0 + sk);
        } else {
            // inline mean10 of n1 rows (identical to old mean_bf16 numerics)
#pragma unroll
            for (int h = 0; h < 2; ++h) {
                const int r = sr + h * 32;
                const size_t gbase = (size_t)(m0 + r) * 10;
                float a0 = 0.f, a1 = 0.f, a2 = 0.f, a3 = 0.f;
                float a4 = 0.f, a5 = 0.f, a6 = 0.f, a7 = 0.f;
#pragma unroll
                for (int j = 0; j < 10; ++j) {
                    const uint4 v = *(const uint4*)(n1rows + (gbase + j) * DF + k0 + sk);
                    a0 += blo(v.x); a1 += bhi(v.x);
                    a2 += blo(v.y); a3 += bhi(v.y);
                    a4 += blo(v.z); a5 += bhi(v.z);
                    a6 += blo(v.w); a7 += bhi(v.w);
                }
                uint4 o;
                o.x = pk2(a0 * 0.1f, a1 * 0.1f);
                o.y = pk2(a2 * 0.1f, a3 * 0.1f);
                o.z = pk2(a4 * 0.1f, a5 * 0.1f);
                o.w = pk2(a6 * 0.1f, a7 * 0.1f);
                *(uint4*)&As[r][sk] = o;
            }
        }
        *(uint4*)&Bs[sr][sk]      = *(const uint4*)(Wt + (size_t)(n0 + sr) * DF + k0 + sk);
        *(uint4*)&Bs[sr + 32][sk] = *(const uint4*)(Wt + (size_t)(n0 + sr + 32) * DF + k0 + sk);
        __syncthreads();
#pragma unroll
        for (int ks = 0; ks < 64; ks += 32) {
            const short8 af = *(const short8*)&As[am][ks + kq];
#pragma unroll
            for (int nt = 0; nt < 4; ++nt) {
                const short8 bf = *(const short8*)&Bs[nt * 16 + (lane & 15)][ks + kq];
                acc[nt] = __builtin_amdgcn_mfma_f32_16x16x32_bf16(af, bf, acc[nt], 0, 0, 0);
            }
        }
        __syncthreads();
    }

#pragma unroll
    for (int nt = 0; nt < 4; ++nt) {
        const int gcol = nb + nt * 16 + (lane & 15);
#pragma unroll
        for (int r = 0; r < 4; ++r) {
            const int grow = m0 + wave * 16 + (lane >> 4) * 4 + r;
            Cout[(size_t)grow * HID2 + gcol] = acc[nt][r];
        }
    }
}

// ---- normalize + prediction head: K split 4 ways across all waves ----------
__global__ __launch_bounds__(256) void normalize_pred(
        const float* __restrict__ outb,
        const float* __restrict__ Wp,
        const float* __restrict__ bp,
        float* __restrict__ logits) {
    __shared__ float row[HID2];
    __shared__ float red[256];
    __shared__ float part[4][64];
    const int r = blockIdx.x;
    const int t = threadIdx.x;
    const float2 v = *(const float2*)(outb + (size_t)r * HID2 + t * 2);
    row[t * 2] = v.x;
    row[t * 2 + 1] = v.y;
    red[t] = v.x * v.x + v.y * v.y;
    __syncthreads();
    for (int s = 128; s > 0; s >>= 1) {
        if (t < s) red[t] += red[t + s];
        __syncthreads();
    }
    const float scale = 1.0f / fmaxf(sqrtf(red[0]), 1e-12f);
    const int c = t & 63;        // output class (valid < 50)
    const int q = t >> 6;        // K-chunk (wave index)
    float acc = 0.f;
    if (c < NCLS) {
#pragma unroll 4
        for (int k = q * 128; k < q * 128 + 128; ++k) acc += row[k] * Wp[k * NCLS + c];
    }
    part[q][c] = acc;
    __syncthreads();
    if (t < NCLS) {
        logits[r * NCLS + t] =
            (part[0][t] + part[1][t] + part[2][t] + part[3][t]) * scale + bp[t];
    }
}

extern "C" void kernel_launch(void* const* d_in, const int* in_sizes, int n_in,
                              void* d_out, int out_size, void* d_ws, size_t ws_size,
                              hipStream_t stream) {
    const float* feat    = (const float*)d_in[0];
    const float* Wself0  = (const float*)d_in[1];
    const float* Wneigh0 = (const float*)d_in[2];
    const float* Wself1  = (const float*)d_in[3];
    const float* Wneigh1 = (const float*)d_in[4];
    const float* Wpred   = (const float*)d_in[5];
    const float* bpred   = (const float*)d_in[6];
    const int* s0 = (const int*)d_in[7];
    const int* s1 = (const int*)d_in[8];
    const int* s2 = (const int*)d_in[9];

    unsigned short* u = (unsigned short*)d_ws;
    unsigned short* h2mean = u;                         // 5120*512
    unsigned short* h1bf   = h2mean + 5120 * 512;       // 5120*512
    unsigned short* n1     = h1bf   + 5120 * 512;       // 5120*512
    unsigned short* h1mean = n1     + 5120 * 512;       // 512*512
    unsigned short* h0bf   = h1mean + 512 * 512;        // 512*512
    unsigned short* n1mean = h0bf   + 512 * 512;        // 512*512 (unused)
    unsigned short* n0     = n1mean + 512 * 512;        // 512*512
    unsigned short* Wt     = n0     + 512 * 512;        // 4 * 256*512
    float* outb = (float*)(Wt + 4 * NHID * DF);         // 512*512 fp32
    unsigned short* Wt_s0 = Wt;
    unsigned short* Wt_n0 = Wt + 1 * NHID * DF;
    unsigned short* Wt_s1 = Wt + 2 * NHID * DF;
    unsigned short* Wt_n1 = Wt + 3 * NHID * DF;

    // L1: all independent preprocessing in one dispatch (heavy blocks first)
    preprocess<<<5760, 256, 0, stream>>>(feat, Wself0, Wneigh0, Wself1, Wneigh1, Wt,
                                         s0, s1, s2, h0bf, h1bf, h1mean, h2mean);
    // L2: n1 (y 0..79) + n0 (y 80..87) fused — independent, share layer-0 weights
    gemm_fused01<<<dim3(8, 88), 256, 0, stream>>>(h1bf, h2mean, h0bf, h1mean,
                                                  Wt_s0, Wt_n0, n1, n0);
    // L3: out = [n0@Ws1, mean10(n1)@Wn1] fp32, n1mean computed inline
    gemm_final<<<dim3(8, 8), 256, 0, stream>>>(n0, n1, Wt_s1, Wt_n1, outb);
    // L4: L2-normalize + prediction head
    normalize_pred<<<NB, 256, 0, stream>>>(outb, Wpred, bpred, (float*)d_out);
}